// Round 3
// baseline (17.055 us; speedup 1.0000x reference)
//
#include <hip/hip_runtime.h>

#define B_ 2
#define L_ 2048
#define H_ 8
#define HD 64
#define K_ 63
#define TQ 32
#define NT (L_ / TQ)          // 64 query tiles per (b,h)
#define ROWS 96               // window union (94 used) padded
#define NKG 6                 // key fragment groups = ROWS/16
#define EXPC 0.1803368801111204f   // scale(=0.125) * log2(e)

typedef __attribute__((ext_vector_type(8))) short bf16x8;   // MFMA A/B operand
typedef __attribute__((ext_vector_type(4))) float f32x4;    // MFMA C/D operand
typedef __attribute__((ext_vector_type(4))) unsigned short u16x4;

// float -> bf16 bits, round-nearest-even
__device__ inline unsigned short f2bf(float f) {
    unsigned u = __float_as_uint(f);
    unsigned r = ((u >> 16) & 1u) + 0x7FFFu;
    return (unsigned short)((u + r) >> 16);
}

// LDS layouts (ushort-indexed, XOR-swizzled at 16B-group granularity):
//  kv [96 keys][64 d]   grp(8 per row) ^= (row & 7)    (QK^T frags; d contiguous)
//  kvT[64 d][128 keys]  grp(16 per row) ^= (d & 15)    (PV B frags; keys contiguous; 96 used)
//  pt [wave][16 q][128 k] grp ^= (q & 15)              (PV A frags) -- ALIASES kv after barrier
//
// MFMA 16x16x32 bf16 lane maps:
//  A: row m = lane&15, k = (lane>>4)*8 + j ; B: col n = lane&15, same k
//  D: col n = lane&15, row m = (lane>>4)*4 + reg
__global__ __launch_bounds__(128, 2) void natten1d_mfma(
    const float* __restrict__ x, float* __restrict__ out)
{
    __shared__ unsigned short smem[ROWS * 64 + 64 * 128];   // kv | kvT (28 KB)
    unsigned short* kv  = smem;
    unsigned short* kvT = smem + ROWS * 64;

    // XCD-chunked swizzle: each XCD owns a contiguous chunk of (b,h,t) work
    const int bid = blockIdx.x;
    const int wid = (bid & 7) * (B_ * H_ * NT / 8) + (bid >> 3);
    const int bh  = wid / NT;
    const int t   = wid % NT;
    const int b   = bh / H_;
    const int h   = bh % H_;
    const int l0  = t * TQ;
    const int key_base = min(max(l0 - K_ / 2, 0), L_ - K_);
    const int qoff     = l0 - key_base;

    const int tid = threadIdx.x;

    // ---- stage: register 4x4 micro-transpose, all-b64 LDS writes ----
    const float4* xb = (const float4*)x + (size_t)b * (L_ * H_ * HD / 4) + h * (HD / 4);
    #pragma unroll
    for (int it = 0; it < 3; ++it) {
        const int mt = tid + it * 128;        // 384 micro-tiles = 24 rowgroups x 16 d4
        const int rg = mt >> 4;
        const int d4 = mt & 15;
        const int r0 = rg * 4;
        unsigned short bf[4][4];
        #pragma unroll
        for (int rr = 0; rr < 4; ++rr) {
            const int g = key_base + r0 + rr;
            float4 v = make_float4(0.f, 0.f, 0.f, 0.f);
            if (g < L_) v = xb[(size_t)g * (H_ * HD / 4) + d4];
            bf[rr][0] = f2bf(v.x); bf[rr][1] = f2bf(v.y);
            bf[rr][2] = f2bf(v.z); bf[rr][3] = f2bf(v.w);
            const int r = r0 + rr;
            *(u16x4*)&kv[r * 64 + (((d4 >> 1) ^ (r & 7)) << 3) + (d4 & 1) * 4] =
                (u16x4){bf[rr][0], bf[rr][1], bf[rr][2], bf[rr][3]};
        }
        #pragma unroll
        for (int e = 0; e < 4; ++e) {
            const int d = d4 * 4 + e;
            *(u16x4*)&kvT[d * 128 + (((rg >> 1) ^ (d & 15)) << 3) + ((rg & 1) << 2)] =
                (u16x4){bf[0][e], bf[1][e], bf[2][e], bf[3][e]};
        }
    }
    __syncthreads();

    const int wave = tid >> 6;
    const int lane = tid & 63;
    const int lq = lane & 15;
    const int lg = lane >> 4;

    // ---- S = Q K^T : 16 queries/wave x 96 keys ----
    bf16x8 aq[2];
    {
        const int qrow = qoff + wave * 16 + lq;
        aq[0] = *(const bf16x8*)&kv[qrow * 64 + ((lg ^ (qrow & 7)) << 3)];
        aq[1] = *(const bf16x8*)&kv[qrow * 64 + (((4 + lg) ^ (qrow & 7)) << 3)];
    }
    f32x4 acc[NKG];
    #pragma unroll
    for (int nb = 0; nb < NKG; ++nb) acc[nb] = (f32x4){0.f, 0.f, 0.f, 0.f};
    #pragma unroll
    for (int nb = 0; nb < NKG; ++nb) {
        const int krow = nb * 16 + lq;
        const bf16x8 b0 = *(const bf16x8*)&kv[krow * 64 + ((lg ^ (krow & 7)) << 3)];
        const bf16x8 b1 = *(const bf16x8*)&kv[krow * 64 + (((4 + lg) ^ (krow & 7)) << 3)];
        acc[nb] = __builtin_amdgcn_mfma_f32_16x16x32_bf16(aq[0], b0, acc[nb], 0, 0, 0);
        acc[nb] = __builtin_amdgcn_mfma_f32_16x16x32_bf16(aq[1], b1, acc[nb], 0, 0, 0);
    }

    __syncthreads();   // all waves done reading kv -> pt may overwrite it

    // ---- band mask + softmax (4 query rows per lane) ----
    float rz[4];
    #pragma unroll
    for (int r = 0; r < 4; ++r) {
        const int q    = wave * 16 + lg * 4 + r;
        const int soff = min(max(l0 + q - K_ / 2, 0), L_ - K_) - key_base;
        float mrow = -1e30f;
        #pragma unroll
        for (int nb = 0; nb < NKG; ++nb) {
            const int col = nb * 16 + lq;
            float s = acc[nb][r];
            s = ((unsigned)(col - soff) <= (unsigned)(K_ - 1)) ? s : -1e30f;
            acc[nb][r] = s;
            mrow = fmaxf(mrow, s);
        }
        #pragma unroll
        for (int o = 1; o <= 8; o <<= 1) mrow = fmaxf(mrow, __shfl_xor(mrow, o));
        float z = 0.f;
        #pragma unroll
        for (int nb = 0; nb < NKG; ++nb) {
            const float e = exp2f((acc[nb][r] - mrow) * EXPC);
            acc[nb][r] = e;                    // unnormalized P
            z += e;
        }
        #pragma unroll
        for (int o = 1; o <= 8; o <<= 1) z += __shfl_xor(z, o);
        rz[r] = 1.0f / z;
    }

    // ---- P -> per-wave LDS tile (aliases kv region) ----
    unsigned short* ptw = smem + wave * 16 * 128;
    #pragma unroll
    for (int nb = 0; nb < NKG; ++nb) {
        #pragma unroll
        for (int r = 0; r < 4; ++r) {
            const int q = lg * 4 + r;
            ptw[q * 128 + ((((nb * 2) + (lq >> 3)) ^ (q & 15)) << 3) + (lq & 7)]
                = f2bf(acc[nb][r]);
        }
    }

    // ---- O = P * KV ----
    bf16x8 ap[3];
    #pragma unroll
    for (int kc = 0; kc < 3; ++kc)
        ap[kc] = *(const bf16x8*)&ptw[lq * 128 + (((kc * 4 + lg) ^ (lq & 15)) << 3)];
    f32x4 o4[4];
    #pragma unroll
    for (int nb = 0; nb < 4; ++nb) o4[nb] = (f32x4){0.f, 0.f, 0.f, 0.f};
    #pragma unroll
    for (int nb = 0; nb < 4; ++nb) {
        const int d = nb * 16 + lq;
        #pragma unroll
        for (int kc = 0; kc < 3; ++kc) {
            const bf16x8 bv = *(const bf16x8*)&kvT[d * 128 + (((kc * 4 + lg) ^ (d & 15)) << 3)];
            o4[nb] = __builtin_amdgcn_mfma_f32_16x16x32_bf16(ap[kc], bv, o4[nb], 0, 0, 0);
        }
    }

    // ---- epilogue: normalize + store fp32 ----
    #pragma unroll
    for (int nb = 0; nb < 4; ++nb) {
        const int d = nb * 16 + lq;
        #pragma unroll
        for (int r = 0; r < 4; ++r) {
            const int q = wave * 16 + lg * 4 + r;
            out[((size_t)(b * L_ + l0 + q) * H_ + h) * HD + d] = o4[nb][r] * rz[r];
        }
    }
}

extern "C" void kernel_launch(void* const* d_in, const int* in_sizes, int n_in,
                              void* d_out, int out_size, void* d_ws, size_t ws_size,
                              hipStream_t stream)
{
    const float* x = (const float*)d_in[0];
    float* out = (float*)d_out;
    natten1d_mfma<<<dim3(B_ * H_ * NT), dim3(128), 0, stream>>>(x, out);
}

// Round 4
// 13.135 us; speedup vs baseline: 1.2984x; 1.2984x over previous
//
#include <hip/hip_runtime.h>

#define B_ 2
#define L_ 2048
#define H_ 8
#define HD 64
#define K_ 63
#define TQ 64
#define NT (L_ / TQ)          // 32 query tiles per (b,h)
#define ROWS 128              // padded window union (126 used)
#define EXPC 0.1803368801111204f   // scale(=hd^-0.5=0.125) * log2(e)

typedef __attribute__((ext_vector_type(8))) short bf16x8;   // MFMA A/B operand
typedef __attribute__((ext_vector_type(4))) float f32x4;    // MFMA C/D operand
typedef __attribute__((ext_vector_type(4))) unsigned short u16x4;

// float -> bf16 bits, round-nearest-even
__device__ inline unsigned short f2bf(float f) {
    unsigned u = __float_as_uint(f);
    unsigned r = ((u >> 16) & 1u) + 0x7FFFu;
    return (unsigned short)((u + r) >> 16);
}

// LDS layouts (ushort-indexed, XOR-swizzled at 16B-group granularity):
//  kv [128 keys][64 d]   grp(8/row)  ^= (row & 7)   (QK^T frags; d contiguous)
//  kvT[64 d][128 keys]   grp(16/row) ^= (d & 15)    (PV B frags; keys contiguous)
//  pt [wave][16 q][128 k] grp ^= (q & 15)           (PV A frags; per-wave private)
//
// MFMA 16x16x32 bf16 lane maps:
//  A: row m = lane&15, k = (lane>>4)*8 + j ; B: col n = lane&15, same k
//  D: col n = lane&15, row m = (lane>>4)*4 + reg
__global__ __launch_bounds__(256) void natten1d_mfma(
    const float* __restrict__ x, float* __restrict__ out)
{
    __shared__ unsigned short kv_sh [ROWS * 64];
    __shared__ unsigned short kvT_sh[64 * ROWS];
    __shared__ unsigned short pt_sh [4 * 16 * ROWS];

    // Bijective XCD-chunked swizzle (512 % 8 == 0): each XCD owns 2 whole
    // (b,h) panels -> neighboring tiles' 2/3-overlapping windows hit L2.
    const int bid = blockIdx.x;
    const int wid = (bid & 7) * (B_ * H_ * NT / 8) + (bid >> 3);
    const int bh  = wid / NT;
    const int t   = wid % NT;
    const int b   = bh / H_;
    const int h   = bh % H_;
    const int l0  = t * TQ;
    const int key_base = min(max(l0 - K_ / 2, 0), L_ - K_);
    const int qoff     = l0 - key_base;          // 0 (first tile) or 31

    const int tid = threadIdx.x;

    // ---- stage: register 4x4 micro-transpose, all-b64 LDS writes ----
    const float4* xb = (const float4*)x + (size_t)b * (L_ * H_ * HD / 4) + h * (HD / 4);
    #pragma unroll
    for (int it = 0; it < 2; ++it) {
        const int mt = tid + it * 256;           // 512 micro-tiles = 32 rg x 16 d4
        const int rg = mt >> 4;
        const int d4 = mt & 15;
        const int r0 = rg * 4;
        unsigned short bf[4][4];
        #pragma unroll
        for (int rr = 0; rr < 4; ++rr) {
            const int g = key_base + r0 + rr;
            float4 v = make_float4(0.f, 0.f, 0.f, 0.f);
            if (g < L_) v = xb[(size_t)g * (H_ * HD / 4) + d4];
            bf[rr][0] = f2bf(v.x); bf[rr][1] = f2bf(v.y);
            bf[rr][2] = f2bf(v.z); bf[rr][3] = f2bf(v.w);
            const int r = r0 + rr;
            *(u16x4*)&kv_sh[r * 64 + (((d4 >> 1) ^ (r & 7)) << 3) + (d4 & 1) * 4] =
                (u16x4){bf[rr][0], bf[rr][1], bf[rr][2], bf[rr][3]};
        }
        #pragma unroll
        for (int e = 0; e < 4; ++e) {
            const int d = d4 * 4 + e;
            *(u16x4*)&kvT_sh[d * 128 + (((rg >> 1) ^ (d & 15)) << 3) + ((rg & 1) << 2)] =
                (u16x4){bf[0][e], bf[1][e], bf[2][e], bf[3][e]};
        }
    }
    __syncthreads();

    const int wave = tid >> 6;
    const int lane = tid & 63;
    const int lq = lane & 15;
    const int lg = lane >> 4;

    // ---- S = Q K^T : 16 queries/wave x 128 keys ----
    bf16x8 aq[2];
    {
        const int qrow = qoff + wave * 16 + lq;
        aq[0] = *(const bf16x8*)&kv_sh[qrow * 64 + ((lg ^ (qrow & 7)) << 3)];
        aq[1] = *(const bf16x8*)&kv_sh[qrow * 64 + (((4 + lg) ^ (qrow & 7)) << 3)];
    }
    f32x4 acc[8];
    #pragma unroll
    for (int nb = 0; nb < 8; ++nb) acc[nb] = (f32x4){0.f, 0.f, 0.f, 0.f};
    #pragma unroll
    for (int nb = 0; nb < 8; ++nb) {
        const int krow = nb * 16 + lq;
        const bf16x8 b0 = *(const bf16x8*)&kv_sh[krow * 64 + ((lg ^ (krow & 7)) << 3)];
        const bf16x8 b1 = *(const bf16x8*)&kv_sh[krow * 64 + (((4 + lg) ^ (krow & 7)) << 3)];
        acc[nb] = __builtin_amdgcn_mfma_f32_16x16x32_bf16(aq[0], b0, acc[nb], 0, 0, 0);
        acc[nb] = __builtin_amdgcn_mfma_f32_16x16x32_bf16(aq[1], b1, acc[nb], 0, 0, 0);
    }

    // ---- band mask + softmax (4 query rows per lane) ----
    float rz[4];
    #pragma unroll
    for (int r = 0; r < 4; ++r) {
        const int q    = wave * 16 + lg * 4 + r;
        const int soff = min(max(l0 + q - K_ / 2, 0), L_ - K_) - key_base;
        float mrow = -1e30f;
        #pragma unroll
        for (int nb = 0; nb < 8; ++nb) {
            const int col = nb * 16 + lq;
            float s = acc[nb][r];
            s = ((unsigned)(col - soff) <= (unsigned)(K_ - 1)) ? s : -1e30f;
            acc[nb][r] = s;
            mrow = fmaxf(mrow, s);
        }
        #pragma unroll
        for (int o = 1; o <= 8; o <<= 1) mrow = fmaxf(mrow, __shfl_xor(mrow, o));
        float z = 0.f;
        #pragma unroll
        for (int nb = 0; nb < 8; ++nb) {
            const float e = exp2f((acc[nb][r] - mrow) * EXPC);
            acc[nb][r] = e;                                   // unnormalized P
            z += e;
        }
        #pragma unroll
        for (int o = 1; o <= 8; o <<= 1) z += __shfl_xor(z, o);
        rz[r] = 1.0f / z;                                     // folded into epilogue
    }

    // ---- P -> per-wave LDS tile (bf16, swizzled; no barrier needed) ----
    unsigned short* ptw = &pt_sh[wave * 16 * 128];
    #pragma unroll
    for (int nb = 0; nb < 8; ++nb) {
        #pragma unroll
        for (int r = 0; r < 4; ++r) {
            const int q = lg * 4 + r;
            ptw[q * 128 + ((((nb * 2) + (lq >> 3)) ^ (q & 15)) << 3) + (lq & 7)]
                = f2bf(acc[nb][r]);
        }
    }

    // ---- O = P * KV ----
    bf16x8 ap[4];
    #pragma unroll
    for (int kc = 0; kc < 4; ++kc)
        ap[kc] = *(const bf16x8*)&ptw[lq * 128 + (((kc * 4 + lg) ^ (lq & 15)) << 3)];
    f32x4 o4[4];
    #pragma unroll
    for (int nb = 0; nb < 4; ++nb) o4[nb] = (f32x4){0.f, 0.f, 0.f, 0.f};
    #pragma unroll
    for (int nb = 0; nb < 4; ++nb) {
        const int d = nb * 16 + lq;
        #pragma unroll
        for (int kc = 0; kc < 4; ++kc) {
            const bf16x8 bv = *(const bf16x8*)&kvT_sh[d * 128 + (((kc * 4 + lg) ^ (d & 15)) << 3)];
            o4[nb] = __builtin_amdgcn_mfma_f32_16x16x32_bf16(ap[kc], bv, o4[nb], 0, 0, 0);
        }
    }

    // ---- epilogue: normalize + store fp32 ----
    #pragma unroll
    for (int nb = 0; nb < 4; ++nb) {
        const int d = nb * 16 + lq;
        #pragma unroll
        for (int r = 0; r < 4; ++r) {
            const int q = wave * 16 + lg * 4 + r;
            out[((size_t)(b * L_ + l0 + q) * H_ + h) * HD + d] = o4[nb][r] * rz[r];
        }
    }
}

extern "C" void kernel_launch(void* const* d_in, const int* in_sizes, int n_in,
                              void* d_out, int out_size, void* d_ws, size_t ws_size,
                              hipStream_t stream)
{
    const float* x = (const float*)d_in[0];
    float* out = (float*)d_out;
    natten1d_mfma<<<dim3(B_ * H_ * NT), dim3(256), 0, stream>>>(x, out);
}

// Round 5
// 11.153 us; speedup vs baseline: 1.5292x; 1.1777x over previous
//
#include <hip/hip_runtime.h>

#define B_ 2
#define L_ 2048
#define H_ 8
#define HD 64
#define K_ 63
#define TQ 64
#define NT (L_ / TQ)          // 32 query tiles per (b,h)
#define ROWS 128              // padded window union (126 used)
#define EXPC 0.1803368801111204f   // scale(=hd^-0.5=0.125) * log2(e)

typedef __attribute__((ext_vector_type(8))) short bf16x8;   // MFMA A/B operand
typedef __attribute__((ext_vector_type(4))) float f32x4;    // MFMA C/D operand

// packed f32x2 -> bf16x2 (RNE), single HW instruction on gfx950
__device__ inline unsigned cvt_pk_bf16(float lo, float hi) {
    unsigned r;
    asm("v_cvt_pk_bf16_f32 %0, %1, %2" : "=v"(r) : "v"(lo), "v"(hi));
    return r;
}

// LDS layouts (ushort-indexed, XOR-swizzled at 16B-group granularity):
//  kv [128 keys][64 d]   grp(8/row)  ^= (row & 7)   (S^T A(K)/B(Q) frags)
//  kvT[64 d][128 keys]   grp(16/row) ^= (d & 15)    (PV B(V) frags)
//  pt [wave][16 q][128 k] grp ^= (q & 15)           (PV A(P) frags, per-wave)
//
// MFMA 16x16x32 bf16 lane maps:
//  A: row m = lane&15, k = (lane>>4)*8 + j ; B: col n = lane&15, same k
//  D: col n = lane&15, row m = (lane>>4)*4 + reg
//
// S^T trick: S^T = K·Q^T -> D col = query = lane&15: each lane owns one
// query's scores at keys wb + nb*16 + (lane>>4)*4 + r  (24 values, 96-key band).
__global__ __launch_bounds__(256, 2) void natten1d_mfma(
    const float* __restrict__ x, float* __restrict__ out)
{
    __shared__ unsigned short kv_sh [ROWS * 64];
    __shared__ unsigned short kvT_sh[64 * ROWS];
    __shared__ unsigned short pt_sh [4 * 16 * 128];

    // Bijective XCD-chunked swizzle (512 % 8 == 0)
    const int bid = blockIdx.x;
    const int wid = (bid & 7) * (B_ * H_ * NT / 8) + (bid >> 3);
    const int bh  = wid / NT;
    const int t   = wid % NT;
    const int b   = bh / H_;
    const int h   = bh % H_;
    const int l0  = t * TQ;
    const int key_base = min(max(l0 - K_ / 2, 0), L_ - K_);
    const int qoff     = l0 - key_base;          // 0 (first tile) or 31

    const int tid = threadIdx.x;
    const int d4  = tid & 15;
    const int rg0 = tid >> 4;                    // 0..15

    // ---- staging: hoist all loads, cvt_pk convert, b64 LDS writes ----
    const float4* xb = (const float4*)x + (size_t)b * (L_ * H_ * HD / 4) + h * (HD / 4);
    float4 ld[8];
    #pragma unroll
    for (int m = 0; m < 2; ++m) {
        const int rg = rg0 + m * 16;
        #pragma unroll
        for (int rr = 0; rr < 4; ++rr) {
            const int g = key_base + rg * 4 + rr;
            ld[m * 4 + rr] = (g < L_) ? xb[(size_t)g * (H_ * HD / 4) + d4]
                                      : make_float4(0.f, 0.f, 0.f, 0.f);
        }
    }
    #pragma unroll
    for (int m = 0; m < 2; ++m) {
        const int rg = rg0 + m * 16;
        #pragma unroll
        for (int rr = 0; rr < 4; ++rr) {
            const int r = rg * 4 + rr;
            const float4 v = ld[m * 4 + rr];
            uint2 w;
            w.x = cvt_pk_bf16(v.x, v.y);
            w.y = cvt_pk_bf16(v.z, v.w);
            *(uint2*)&kv_sh[r * 64 + (((d4 >> 1) ^ (r & 7)) << 3) + (d4 & 1) * 4] = w;
        }
        #pragma unroll
        for (int e = 0; e < 4; ++e) {
            const int d = d4 * 4 + e;
            const float* f0 = (const float*)&ld[m * 4 + 0];
            const float* f1 = (const float*)&ld[m * 4 + 1];
            const float* f2 = (const float*)&ld[m * 4 + 2];
            const float* f3 = (const float*)&ld[m * 4 + 3];
            uint2 w;
            w.x = cvt_pk_bf16(f0[e], f1[e]);
            w.y = cvt_pk_bf16(f2[e], f3[e]);
            *(uint2*)&kvT_sh[d * 128 + (((rg >> 1) ^ (d & 15)) << 3) + ((rg & 1) << 2)] = w;
        }
    }
    __syncthreads();

    const int wave = tid >> 6;
    const int lane = tid & 63;
    const int lq = lane & 15;          // query index (S^T) / d-within-block (PV out)
    const int lg = lane >> 4;

    // ---- per-wave 96-key band window ----
    const int q0    = wave * 16;
    const int soff0 = min(max(l0 + q0 - K_ / 2, 0), L_ - K_) - key_base;
    const int wb    = min(soff0 & ~15, ROWS - 96);          // 16-aligned, band-covering
    const int qrow  = qoff + q0 + lq;
    const int soffq = min(max(l0 + q0 + lq - K_ / 2, 0), L_ - K_) - key_base;
    const int cbase = wb + lg * 4 - soffq;                  // mask helper

    // ---- S^T = K * Q^T over 96 keys ----
    bf16x8 bq[2];
    bq[0] = *(const bf16x8*)&kv_sh[qrow * 64 + ((lg ^ (qrow & 7)) << 3)];
    bq[1] = *(const bf16x8*)&kv_sh[qrow * 64 + (((4 + lg) ^ (qrow & 7)) << 3)];

    f32x4 acc[6];
    #pragma unroll
    for (int nb = 0; nb < 6; ++nb) acc[nb] = (f32x4){0.f, 0.f, 0.f, 0.f};
    #pragma unroll
    for (int nb = 0; nb < 6; ++nb) {
        const int krow = wb + nb * 16 + lq;
        const bf16x8 a0 = *(const bf16x8*)&kv_sh[krow * 64 + ((lg ^ (krow & 7)) << 3)];
        const bf16x8 a1 = *(const bf16x8*)&kv_sh[krow * 64 + (((4 + lg) ^ (krow & 7)) << 3)];
        acc[nb] = __builtin_amdgcn_mfma_f32_16x16x32_bf16(a0, bq[0], acc[nb], 0, 0, 0);
        acc[nb] = __builtin_amdgcn_mfma_f32_16x16x32_bf16(a1, bq[1], acc[nb], 0, 0, 0);
    }

    // ---- per-lane softmax (one query per lane; 2 shfl per reduce) ----
    float mx = -1e30f;
    #pragma unroll
    for (int nb = 0; nb < 6; ++nb) {
        #pragma unroll
        for (int r = 0; r < 4; ++r) {
            const bool valid = (unsigned)(cbase + nb * 16 + r) < (unsigned)K_;
            const float s = valid ? acc[nb][r] : -1e30f;
            acc[nb][r] = s;
            mx = fmaxf(mx, s);
        }
    }
    mx = fmaxf(mx, __shfl_xor(mx, 16));
    mx = fmaxf(mx, __shfl_xor(mx, 32));
    float z = 0.f;
    #pragma unroll
    for (int nb = 0; nb < 6; ++nb) {
        #pragma unroll
        for (int r = 0; r < 4; ++r) {
            const float e = exp2f((acc[nb][r] - mx) * EXPC);
            acc[nb][r] = e;
            z += e;
        }
    }
    z += __shfl_xor(z, 16);
    z += __shfl_xor(z, 32);
    const float rz = 1.0f / z;

    // ---- normalized P -> per-wave pt tile (b64 writes; key-quads lane-local) ----
    unsigned short* ptw = &pt_sh[wave * 16 * 128];
    #pragma unroll
    for (int nb = 0; nb < 6; ++nb) {
        uint2 w;
        w.x = cvt_pk_bf16(acc[nb][0] * rz, acc[nb][1] * rz);
        w.y = cvt_pk_bf16(acc[nb][2] * rz, acc[nb][3] * rz);
        const int g = nb * 2 + (lg >> 1);
        *(uint2*)&ptw[lq * 128 + ((g ^ lq) << 3) + ((lg & 1) << 2)] = w;
    }

    // ---- O = P * V over the 96-key band ----
    bf16x8 ap[3];
    #pragma unroll
    for (int kc = 0; kc < 3; ++kc)
        ap[kc] = *(const bf16x8*)&ptw[lq * 128 + (((kc * 4 + lg) ^ lq) << 3)];
    f32x4 o4[4];
    #pragma unroll
    for (int nb = 0; nb < 4; ++nb) o4[nb] = (f32x4){0.f, 0.f, 0.f, 0.f};
    const int kg0 = wb >> 3;
    #pragma unroll
    for (int nb = 0; nb < 4; ++nb) {
        const int d = nb * 16 + lq;
        #pragma unroll
        for (int kc = 0; kc < 3; ++kc) {
            const bf16x8 bv =
                *(const bf16x8*)&kvT_sh[d * 128 + (((kg0 + kc * 4 + lg) ^ (d & 15)) << 3)];
            o4[nb] = __builtin_amdgcn_mfma_f32_16x16x32_bf16(ap[kc], bv, o4[nb], 0, 0, 0);
        }
    }

    // ---- epilogue: store fp32 (already normalized) ----
    #pragma unroll
    for (int nb = 0; nb < 4; ++nb) {
        const int d = nb * 16 + lq;
        #pragma unroll
        for (int r = 0; r < 4; ++r) {
            const int q = q0 + lg * 4 + r;
            out[((size_t)(b * L_ + l0 + q) * H_ + h) * HD + d] = o4[nb][r];
        }
    }
}

extern "C" void kernel_launch(void* const* d_in, const int* in_sizes, int n_in,
                              void* d_out, int out_size, void* d_ws, size_t ws_size,
                              hipStream_t stream)
{
    const float* x = (const float*)d_in[0];
    float* out = (float*)d_out;
    natten1d_mfma<<<dim3(B_ * H_ * NT), dim3(256), 0, stream>>>(x, out);
}